// Round 2
// 205.377 us; speedup vs baseline: 1.0011x; 1.0011x over previous
//
#include <hip/hip_runtime.h>

// GatherBlock: out[m, c, y, xw] = x[b[m], c, yb[m]*16 + y, xb[m]*16 + xw]
// N=8, C=64, H=256, W=256, BH=BW=16, M=1024. fp32.
//
// Layout (float4 units): W/4 = 64 float4 per input row; BW/4 = 4 float4 per
// block row. Each output block m = 64*16*16 floats = 4096 float4.
// 8 thread-blocks of 256 threads per m, TWO float4 per thread
// (2x memory-level parallelism, half the waves), non-temporal stores so the
// 64 MiB write-once output stream doesn't evict gather read lines in L2/L3.
// m = blockIdx.x >> 3 is block-uniform -> index loads compile to s_load.
//
// NOTE: __builtin_nontemporal_store requires a native Clang vector type,
// not HIP_vector_type<float,4> -> use ext_vector_type(4).

typedef float vfloat4 __attribute__((ext_vector_type(4)));

__global__ __launch_bounds__(256) void gather_block_kernel(
    const vfloat4* __restrict__ x,
    const int* __restrict__ idx,
    vfloat4* __restrict__ out) {
  const int m  = blockIdx.x >> 3;
  const int b  = idx[3 * m + 0];
  const int yb = idx[3 * m + 1];
  const int xb = idx[3 * m + 2];

  // base covers 0..4095 in two halves: [512k + tid] and [512k + 256 + tid]
  const int base = ((blockIdx.x & 7) << 9) | threadIdx.x;  // lower half

  const int xw4 = base & 3;          // float4 col within block row (0..3)
  const int y   = (base >> 2) & 15;  // row within block (0..15)
  const int c   = base >> 6;         // channel (0..59 for lower half)

  // input address in float4 units: ((b*C + c)*H + yb*16 + y)*(W/4) + xb*4 + xw4
  const long long in4 =
      ((long long)((b << 6) + c) * 256 + (yb << 4) + y) * 64 + (xb << 2) + xw4;

  // Second element: base+256 -> c+4, same y/xw4 -> +4*H*(W/4) = +65536 float4.
  const vfloat4 v0 = x[in4];
  const vfloat4 v1 = x[in4 + 65536];

  const long long o = ((long long)m << 12) + base;
  __builtin_nontemporal_store(v0, &out[o]);
  __builtin_nontemporal_store(v1, &out[o + 256]);
}

extern "C" void kernel_launch(void* const* d_in, const int* in_sizes, int n_in,
                              void* d_out, int out_size, void* d_ws, size_t ws_size,
                              hipStream_t stream) {
  const vfloat4* x  = (const vfloat4*)d_in[0];
  const int* idx    = (const int*)d_in[1];
  vfloat4* out      = (vfloat4*)d_out;

  // M * (C*BH*BW/4 float4) / (256 threads * 2 float4/thread) = 1024 * 8 = 8192 blocks
  gather_block_kernel<<<8192, 256, 0, stream>>>(x, idx, out);
}